// Round 4
// baseline (13.008 us; speedup 1.0000x reference)
//
#include <hip/hip_runtime.h>

// Body3 Euler-Lagrange EOM, analytically reduced:
//   dvL = v  (m=1)  =>  dvdvL = I, dxdvL = 0  =>  a = dxL
//   a_i = -sum_{j != i} (p_i - p_j)/|p_i - p_j|^3   (k=1, m=1)
//   out = [v, a]
//
// Loads: direct strided float4 (every byte of each line is consumed by the
// wave; L1 serves the overlap — staging them through LDS bought nothing).
// Stores: LDS-staged so the wave writes 4 KB contiguous per store instr
// (full-line writes, no L2 read-modify-write).
__global__ __launch_bounds__(256) void body3_eom_kernel(
    const float4* __restrict__ gin, float4* __restrict__ gout, int bs) {
  __shared__ float4 lds4[768];  // 256 samples * 3 float4 = 12 KB
  const int tid = threadIdx.x;
  const int s0 = blockIdx.x * 256;                // first sample of this block
  const size_t base4 = (size_t)blockIdx.x * 768;  // first float4 of this block
  const int idx = s0 + tid;

  if (idx < bs) {
    const float4* cin = gin + (size_t)idx * 3;
    float4 c0 = cin[0];  // x0 y0 x1 y1
    float4 c1 = cin[1];  // x2 y2 v0x v0y
    float4 c2 = cin[2];  // v1x v1y v2x v2y

    float x0 = c0.x, y0 = c0.y, x1 = c0.z, y1 = c0.w;
    float x2 = c1.x, y2 = c1.y;

    float d01x = x0 - x1, d01y = y0 - y1;
    float d02x = x0 - x2, d02y = y0 - y2;
    float d12x = x1 - x2, d12y = y1 - y2;

    float r01_2 = d01x * d01x + d01y * d01y;
    float r02_2 = d02x * d02x + d02y * d02y;
    float r12_2 = d12x * d12x + d12y * d12y;

    float ir01 = rsqrtf(r01_2);
    float ir02 = rsqrtf(r02_2);
    float ir12 = rsqrtf(r12_2);

    float c01 = ir01 * ir01 * ir01;  // 1/r^3
    float c02 = ir02 * ir02 * ir02;
    float c12 = ir12 * ir12 * 12 == 0 ? 0.f : ir12 * ir12 * ir12; // (see below)
    c12 = ir12 * ir12 * ir12;

    float a0x = -(d01x * c01 + d02x * c02);
    float a0y = -(d01y * c01 + d02y * c02);
    float a1x = d01x * c01 - d12x * c12;
    float a1y = d01y * c01 - d12y * c12;
    float a2x = d02x * c02 + d12x * c12;
    float a2y = d02y * c02 + d12y * c12;

    float4 o0;  // v0x v0y v1x v1y
    o0.x = c1.z; o0.y = c1.w; o0.z = c2.x; o0.w = c2.y;
    float4 o1;  // v2x v2y a0x a0y
    o1.x = c2.z; o1.y = c2.w; o1.z = a0x; o1.w = a0y;
    float4 o2;  // a1x a1y a2x a2y
    o2.x = a1x; o2.y = a1y; o2.z = a2x; o2.w = a2y;
    lds4[tid * 3 + 0] = o0;
    lds4[tid * 3 + 1] = o1;
    lds4[tid * 3 + 2] = o2;
  }
  __syncthreads();

  const size_t lim4 = (size_t)bs * 3;
#pragma unroll
  for (int k = 0; k < 3; ++k) {
    size_t f = base4 + (size_t)(k * 256) + tid;
    if (f < lim4) gout[f] = lds4[k * 256 + tid];
  }
}

extern "C" void kernel_launch(void* const* d_in, const int* in_sizes, int n_in,
                              void* d_out, int out_size, void* d_ws, size_t ws_size,
                              hipStream_t stream) {
  // d_in[0] = t (unused, size 1), d_in[1] = coords [bs, 12] f32
  const float4* coords = (const float4*)d_in[1];
  float4* out = (float4*)d_out;
  int bs = in_sizes[1] / 12;
  int grid = (bs + 255) / 256;
  body3_eom_kernel<<<grid, 256, 0, stream>>>(coords, out, bs);
}

// Round 5
// 12.122 us; speedup vs baseline: 1.0731x; 1.0731x over previous
//
#include <hip/hip_runtime.h>

// Body3 Euler-Lagrange EOM, analytically reduced:
//   dvL = v  (m=1)  =>  dvdvL = I, dxdvL = 0  =>  a = dxL
//   a_i = -sum_{j != i} (p_i - p_j)/|p_i - p_j|^3   (k=1, m=1)
//   out = [v, a]
//
// Best-measured structure (R2): LDS-staged on BOTH sides so every global
// load and store instruction is pure lane-linear (1 KB/instr, full-line
// writes, no L2 RMW). Measured 12.31 us vs 15.5 direct / 13.0 store-only.
__global__ __launch_bounds__(256) void body3_eom_kernel(
    const float4* __restrict__ gin, float4* __restrict__ gout, int bs) {
  __shared__ float lds[3072];  // 256 samples * 12 floats = 12 KB
  float4* lds4 = reinterpret_cast<float4*>(lds);
  const int tid = threadIdx.x;
  const int s0 = blockIdx.x * 256;               // first sample of this block
  const size_t base4 = (size_t)blockIdx.x * 768; // first float4 of this block
  const bool full = (s0 + 256 <= bs);            // block-uniform
  const bool active = (s0 + tid < bs);

  if (full) {
#pragma unroll
    for (int k = 0; k < 3; ++k)
      lds4[k * 256 + tid] = gin[base4 + (size_t)(k * 256) + tid];
  } else if (active) {
#pragma unroll
    for (int k = 0; k < 3; ++k)
      lds4[tid * 3 + k] = gin[(size_t)(s0 + tid) * 3 + k];
  }
  __syncthreads();

  if (active) {
    float* s = lds + tid * 12;
    float4 c0 = reinterpret_cast<float4*>(s)[0];  // x0 y0 x1 y1
    float4 c1 = reinterpret_cast<float4*>(s)[1];  // x2 y2 v0x v0y
    float4 c2 = reinterpret_cast<float4*>(s)[2];  // v1x v1y v2x v2y

    float x0 = c0.x, y0 = c0.y, x1 = c0.z, y1 = c0.w;
    float x2 = c1.x, y2 = c1.y;

    float d01x = x0 - x1, d01y = y0 - y1;
    float d02x = x0 - x2, d02y = y0 - y2;
    float d12x = x1 - x2, d12y = y1 - y2;

    float r01_2 = d01x * d01x + d01y * d01y;
    float r02_2 = d02x * d02x + d02y * d02y;
    float r12_2 = d12x * d12x + d12y * d12y;

    float ir01 = rsqrtf(r01_2);
    float ir02 = rsqrtf(r02_2);
    float ir12 = rsqrtf(r12_2);

    float c01 = ir01 * ir01 * ir01;  // 1/r^3
    float c02 = ir02 * ir02 * ir02;
    float c12 = ir12 * ir12 * ir12;

    float a0x = -(d01x * c01 + d02x * c02);
    float a0y = -(d01y * c01 + d02y * c02);
    float a1x = d01x * c01 - d12x * c12;
    float a1y = d01y * c01 - d12y * c12;
    float a2x = d02x * c02 + d12x * c12;
    float a2y = d02y * c02 + d12y * c12;

    float4 o0;  // v0x v0y v1x v1y
    o0.x = c1.z; o0.y = c1.w; o0.z = c2.x; o0.w = c2.y;
    float4 o1;  // v2x v2y a0x a0y
    o1.x = c2.z; o1.y = c2.w; o1.z = a0x; o1.w = a0y;
    float4 o2;  // a1x a1y a2x a2y
    o2.x = a1x; o2.y = a1y; o2.z = a2x; o2.w = a2y;
    reinterpret_cast<float4*>(s)[0] = o0;
    reinterpret_cast<float4*>(s)[1] = o1;
    reinterpret_cast<float4*>(s)[2] = o2;
  }
  __syncthreads();

  if (full) {
#pragma unroll
    for (int k = 0; k < 3; ++k)
      gout[base4 + (size_t)(k * 256) + tid] = lds4[k * 256 + tid];
  } else if (active) {
#pragma unroll
    for (int k = 0; k < 3; ++k)
      gout[(size_t)(s0 + tid) * 3 + k] = lds4[tid * 3 + k];
  }
}

extern "C" void kernel_launch(void* const* d_in, const int* in_sizes, int n_in,
                              void* d_out, int out_size, void* d_ws, size_t ws_size,
                              hipStream_t stream) {
  // d_in[0] = t (unused, size 1), d_in[1] = coords [bs, 12] f32
  const float4* coords = (const float4*)d_in[1];
  float4* out = (float4*)d_out;
  int bs = in_sizes[1] / 12;
  int grid = (bs + 255) / 256;
  body3_eom_kernel<<<grid, 256, 0, stream>>>(coords, out, bs);
}